// Round 3
// baseline (240.917 us; speedup 1.0000x reference)
//
#include <hip/hip_runtime.h>

// SimpleDialogGNN on MI355X.
// Pipeline:
//   K0 transpose_pack : W_self,W_msg -> wt_cat (N=1024 x K=2048, bf16, N-major)
//                       W_out        -> wt_out (1024x1024 bf16, N-major)
//   K1 msg_pack       : per-row windowed weighted avg; writes xcat rows
//                       [x_bf16(1024) | msg_bf16(1024)]  (M=8192 x 2048 bf16)
//   K2 gemm<2048,EPI1>: h = xcat @ wt_cat^T + b_self + b_msg;
//                       out = (t<dia_len[b]) ? h : x; r = relu(out) -> bf16
//   K3 gemm<1024,EPI2>: z = x + r @ wt_out^T + b_out -> fp32 zbuf
//   K4 ln_kernel      : LayerNorm(z) * gamma + beta -> d_out (fp32)
//
// GEMM (this round): 8-phase-style template adapted to M=8192,N=1024:
//   BM=256, BN=128, BK=64, 512 thr (8 waves, 4Mx2N, 64x64 C each).
//   Grid 256 = 1 block/CU. 3-deep rotating LDS tiles (144 KiB), T4 counted
//   vmcnt(6) (stage tile t+2 during tile t), 4 phases/tile x 8 MFMA each,
//   T2 slot^=(row&7) XOR swizzle (pre-swizzled global src, linear LDS dest,
//   swizzled ds_read), T5 setprio around MFMA clusters, T1 XCD swizzle.
//
// ws layout (bytes): [0,32M) xcat (bf16)  — aliased by zbuf (fp32) after GEMM1
//                    [32M,48M) r (bf16)
//                    [48M,52M) wt_cat     [52M,54M) wt_out
// total ws required: 54 MiB.

typedef unsigned short u16;
typedef float floatx4 __attribute__((ext_vector_type(4)));
typedef short shortx8 __attribute__((ext_vector_type(8)));

#define T_ 1024
#define H_ 1024

__device__ __forceinline__ float bf2f(u16 v) {
    return __uint_as_float(((unsigned)v) << 16);
}
__device__ __forceinline__ u16 f2bf(float f) {  // round-to-nearest-even
    unsigned u = __float_as_uint(f);
    return (u16)((u + 0x7fffu + ((u >> 16) & 1u)) >> 16);
}
__device__ __forceinline__ void async16(const void* g, void* l) {
    __builtin_amdgcn_global_load_lds(
        (__attribute__((address_space(1))) void*)g,
        (__attribute__((address_space(3))) void*)l, 16, 0, 0);
}
__device__ __forceinline__ void barrier_mem() {
    asm volatile("" ::: "memory");
    __builtin_amdgcn_s_barrier();
    asm volatile("" ::: "memory");
}

// ---------------- K0: transpose + fp32->bf16 pack of the three weights ------
__global__ __launch_bounds__(256)
void transpose_pack(const float* __restrict__ Wself, const float* __restrict__ Wmsg,
                    const float* __restrict__ Wout,
                    u16* __restrict__ wt_cat, u16* __restrict__ wt_out)
{
    __shared__ float s[32][33];
    const int wid = blockIdx.z;
    const float* src = (wid == 0) ? Wself : ((wid == 1) ? Wmsg : Wout);
    const int n0 = blockIdx.x * 32, k0 = blockIdx.y * 32;
    const int tx = threadIdx.x & 31, ty = threadIdx.x >> 5;  // 32x8
#pragma unroll
    for (int i = 0; i < 4; ++i) {
        int k = k0 + ty + 8 * i;
        s[ty + 8 * i][tx] = src[(size_t)k * H_ + n0 + tx];
    }
    __syncthreads();
#pragma unroll
    for (int i = 0; i < 4; ++i) {
        int n = n0 + ty + 8 * i;
        u16 v = f2bf(s[tx][ty + 8 * i]);
        if (wid < 2) wt_cat[(size_t)n * 2048 + wid * 1024 + k0 + tx] = v;
        else         wt_out[(size_t)n * 1024 + k0 + tx] = v;
    }
}

// ---------------- K1: message aggregation + bf16 pack ------------------------
__global__ __launch_bounds__(256)
void msg_pack(const float* __restrict__ x, const float* __restrict__ qmask,
              const int* __restrict__ dia_len, u16* __restrict__ xcat)
{
    __shared__ u16 sx[32][1024];  // 64 KiB
    const int tid = threadIdx.x;
    const int b = blockIdx.y;
    const int t0 = blockIdx.x * 16;
    const int dlen = dia_len[b];
    const int c4 = tid * 4;
    const float* xb = x + (size_t)b * T_ * H_;

    unsigned spkmask = 0;
#pragma unroll 4
    for (int r = 0; r < 32; ++r) {
        int row = t0 - 8 + r;
        row = row < 0 ? 0 : (row > T_ - 1 ? T_ - 1 : row);
        const float* q = qmask + ((size_t)b * T_ + row) * 2;
        spkmask |= (q[1] > q[0] ? 1u : 0u) << r;
        float4 v = *(const float4*)(xb + (size_t)row * H_ + c4);
        ushort4 u;
        u.x = f2bf(v.x); u.y = f2bf(v.y); u.z = f2bf(v.z); u.w = f2bf(v.w);
        *(ushort4*)&sx[r][c4] = u;
    }
    __syncthreads();

    for (int lt = 0; lt < 16; ++lt) {
        const int t = t0 + lt;
        const unsigned cs = (spkmask >> (lt + 8)) & 1u;
        float a0 = 0.f, a1 = 0.f, a2 = 0.f, a3 = 0.f;
        int cnt = 0;
#pragma unroll
        for (int o = 0; o < 17; ++o) {
            const int idx = t + o - 8;
            if (idx >= 0 && idx < dlen) {  // block-uniform branch
                const float w = (((spkmask >> (lt + o)) & 1u) == cs) ? 1.0f : 0.5f;
                ++cnt;
                ushort4 u = *(const ushort4*)&sx[lt + o][c4];
                a0 += w * bf2f(u.x); a1 += w * bf2f(u.y);
                a2 += w * bf2f(u.z); a3 += w * bf2f(u.w);
            }
        }
        const float inv = 1.0f / (float)(cnt > 0 ? cnt : 1);
        ushort4 m;
        m.x = f2bf(a0 * inv); m.y = f2bf(a1 * inv);
        m.z = f2bf(a2 * inv); m.w = f2bf(a3 * inv);
        const size_t rowg = (size_t)b * T_ + t;
        *(ushort4*)&xcat[rowg * 2048 + 1024 + c4] = m;
        *(ushort4*)&xcat[rowg * 2048 + c4] = *(const ushort4*)&sx[lt + 8][c4];
    }
}

// ---------------- K2/K3: bf16 MFMA GEMM, 8-phase-style, BM=256 BN=128 BK=64 --
// A: M x K row-major bf16; Bt: N x K row-major bf16 (N-major).
// LDS swizzle (T2): logical (row, 16B-slot s) lives at LDS slot s^(row&7).
// Staged with linear LDS dest + pre-swizzled global source (involution).
template <int K, int EPI>
__global__ __launch_bounds__(512)
void gemm_bt(const u16* __restrict__ A, const u16* __restrict__ Bt,
             const float* __restrict__ bias1, const float* __restrict__ bias2,
             const float* __restrict__ X, const int* __restrict__ dia_len,
             u16* __restrict__ Rout, float* __restrict__ Zout)
{
    constexpr int NT = K / 64;
    __shared__ u16 sA[3][256 * 64];  // 96 KiB
    __shared__ u16 sB[3][128 * 64];  // 48 KiB
    const int tid = threadIdx.x;

    // T1: XCD-aware block swizzle. bid%8 = XCD; each XCD gets 4 contiguous
    // m-panels x all 8 n-tiles so A-panels are fetched once per XCD L2.
    const int bid = blockIdx.x;
    const int li = bid >> 3;                   // 0..31 within XCD
    const int mt = (bid & 7) * 4 + (li >> 3);  // 0..31
    const int nt = li & 7;                     // 0..7
    const int bm = mt * 256, bn = nt * 128;

    const int wave = tid >> 6, lane = tid & 63;
    const int wr = wave >> 1, wc = wave & 1;   // 4M x 2N waves
    const int lrow = lane & 15, lq = lane >> 4;

    // ---- staging (global -> LDS), pre-swizzled source ----
    const int srow = tid >> 3;                 // 0..63 rows per 8KB chunk
    const int sl   = (tid & 7) ^ (srow & 7);   // swizzled 16B slot in row
    const u16* Asrc = A + (size_t)(bm + srow) * K + sl * 8;
    const u16* Bsrc = Bt + (size_t)(bn + srow) * K + sl * 8;

    auto stageA = [&](int t, int buf, int q) {  // q = 0..3 (64-row quarters)
        async16(Asrc + (size_t)q * 64 * K + t * 64,
                &sA[buf][q * 4096 + tid * 8]);
    };
    auto stageB = [&](int t, int buf, int h) {  // h = 0..1 (64-row halves)
        async16(Bsrc + (size_t)h * 64 * K + t * 64,
                &sB[buf][h * 4096 + tid * 8]);
    };

    floatx4 acc[4][4];
#pragma unroll
    for (int i = 0; i < 4; ++i)
#pragma unroll
        for (int j = 0; j < 4; ++j)
            acc[i][j] = (floatx4){0.f, 0.f, 0.f, 0.f};

    // ---- compute-side LDS read offsets (elements) ----
    const int xk = lrow & 7;
    const int paBase = (wr * 64 + lrow) * 64;
    const int pbBase = (wc * 64 + lrow) * 64;
    const int s0 = ((lq) ^ xk) * 8;        // k-half 0 slot byte-offset/2
    const int s1 = ((4 + lq) ^ xk) * 8;    // k-half 1

    // ---- prologue: stage tiles 0 and 1 (12 loads/wave in flight) ----
#pragma unroll
    for (int q = 0; q < 4; ++q) stageA(0, 0, q);
    stageB(0, 0, 0); stageB(0, 0, 1);
#pragma unroll
    for (int q = 0; q < 4; ++q) stageA(1, 1, q);
    stageB(1, 1, 0); stageB(1, 1, 1);
    asm volatile("s_waitcnt vmcnt(6)" ::: "memory");  // tile 0 landed
    barrier_mem();

    int cur = 0, stg = 2;  // compute buffer, staging buffer ((t+2)%3)
    for (int t = 0; t < NT; ++t) {
        const u16* curA = &sA[cur][0];
        const u16* curB = &sB[cur][0];
        const bool more = (t + 2 < NT);
        shortx8 a0[4], b0[4], a1[4], b1[4];

        // ---- phase 0: B(h0) + A[0..1](h0) reads; stage A q0,q1; MFMA i=0,1 h0
#pragma unroll
        for (int j = 0; j < 4; ++j)
            b0[j] = *(const shortx8*)(curB + pbBase + j * 1024 + s0);
#pragma unroll
        for (int i = 0; i < 2; ++i)
            a0[i] = *(const shortx8*)(curA + paBase + i * 1024 + s0);
        if (more) { stageA(t + 2, stg, 0); stageA(t + 2, stg, 1); }
        barrier_mem();
        __builtin_amdgcn_s_setprio(1);
#pragma unroll
        for (int i = 0; i < 2; ++i)
#pragma unroll
            for (int j = 0; j < 4; ++j)
                acc[i][j] = __builtin_amdgcn_mfma_f32_16x16x32_bf16(
                    a0[i], b0[j], acc[i][j], 0, 0, 0);
        __builtin_amdgcn_s_setprio(0);
        barrier_mem();

        // ---- phase 1: A[2..3](h0) reads; stage A q2,q3; MFMA i=2,3 h0
#pragma unroll
        for (int i = 2; i < 4; ++i)
            a0[i] = *(const shortx8*)(curA + paBase + i * 1024 + s0);
        if (more) { stageA(t + 2, stg, 2); stageA(t + 2, stg, 3); }
        barrier_mem();
        __builtin_amdgcn_s_setprio(1);
#pragma unroll
        for (int i = 2; i < 4; ++i)
#pragma unroll
            for (int j = 0; j < 4; ++j)
                acc[i][j] = __builtin_amdgcn_mfma_f32_16x16x32_bf16(
                    a0[i], b0[j], acc[i][j], 0, 0, 0);
        __builtin_amdgcn_s_setprio(0);
        barrier_mem();

        // ---- phase 2: B(h1) + A[0..1](h1) reads; stage B h0,h1; MFMA i=0,1 h1
#pragma unroll
        for (int j = 0; j < 4; ++j)
            b1[j] = *(const shortx8*)(curB + pbBase + j * 1024 + s1);
#pragma unroll
        for (int i = 0; i < 2; ++i)
            a1[i] = *(const shortx8*)(curA + paBase + i * 1024 + s1);
        if (more) { stageB(t + 2, stg, 0); stageB(t + 2, stg, 1); }
        barrier_mem();
        __builtin_amdgcn_s_setprio(1);
#pragma unroll
        for (int i = 0; i < 2; ++i)
#pragma unroll
            for (int j = 0; j < 4; ++j)
                acc[i][j] = __builtin_amdgcn_mfma_f32_16x16x32_bf16(
                    a1[i], b1[j], acc[i][j], 0, 0, 0);
        __builtin_amdgcn_s_setprio(0);
        barrier_mem();

        // ---- phase 3: A[2..3](h1) reads; MFMA i=2,3 h1; tile handoff
#pragma unroll
        for (int i = 2; i < 4; ++i)
            a1[i] = *(const shortx8*)(curA + paBase + i * 1024 + s1);
        barrier_mem();
        __builtin_amdgcn_s_setprio(1);
#pragma unroll
        for (int i = 2; i < 4; ++i)
#pragma unroll
            for (int j = 0; j < 4; ++j)
                acc[i][j] = __builtin_amdgcn_mfma_f32_16x16x32_bf16(
                    a1[i], b1[j], acc[i][j], 0, 0, 0);
        __builtin_amdgcn_s_setprio(0);

        if (t < NT - 1) {
            // confirm tile t+1's 6 loads landed; keep tile t+2's 6 in flight
            if (more) asm volatile("s_waitcnt vmcnt(6)" ::: "memory");
            else      asm volatile("s_waitcnt vmcnt(0)" ::: "memory");
            barrier_mem();  // after this, tile t+1 globally ready
        }
        cur = (cur == 2) ? 0 : cur + 1;
        stg = (stg == 2) ? 0 : stg + 1;
    }

    // epilogue — C/D mapping: col = lane&15, row = (lane>>4)*4 + reg
    const int dl = (EPI == 1) ? dia_len[bm >> 10] : 0;  // b uniform (256|1024)
#pragma unroll
    for (int i = 0; i < 4; ++i) {
        const int row0 = bm + wr * 64 + i * 16 + lq * 4;
#pragma unroll
        for (int j = 0; j < 4; ++j) {
            const int col = bn + wc * 64 + j * 16 + lrow;
#pragma unroll
            for (int r = 0; r < 4; ++r) {
                const int row = row0 + r;
                const float v = acc[i][j][r];
                if (EPI == 1) {
                    const float h = v + bias1[col] + bias2[col];
                    float outv;
                    if ((row & (T_ - 1)) < dl) {
                        outv = h;  // majority path: no X read
                    } else {
                        outv = X[(size_t)row * H_ + col];
                    }
                    Rout[(size_t)row * H_ + col] = f2bf(fmaxf(outv, 0.f));
                } else {
                    const float z = X[(size_t)row * H_ + col] + v + bias1[col];
                    Zout[(size_t)row * H_ + col] = z;
                }
            }
        }
    }
}

// ---------------- K4: LayerNorm ---------------------------------------------
__global__ __launch_bounds__(256)
void ln_kernel(const float* __restrict__ Z, const float* __restrict__ gamma,
               const float* __restrict__ beta, float* __restrict__ out)
{
    const int row = blockIdx.x;
    const int tid = threadIdx.x;
    const size_t base = (size_t)row * H_ + tid * 4;
    float4 v = *(const float4*)(Z + base);
    float s = v.x + v.y + v.z + v.w;
    float q = v.x * v.x + v.y * v.y + v.z * v.z + v.w * v.w;
#pragma unroll
    for (int off = 32; off > 0; off >>= 1) {
        s += __shfl_down(s, off);
        q += __shfl_down(q, off);
    }
    __shared__ float ps[4], pq[4];
    const int wave = tid >> 6, lane = tid & 63;
    if (lane == 0) { ps[wave] = s; pq[wave] = q; }
    __syncthreads();
    const float S = ps[0] + ps[1] + ps[2] + ps[3];
    const float Q = pq[0] + pq[1] + pq[2] + pq[3];
    const float mean = S * (1.0f / 1024.0f);
    const float var = Q * (1.0f / 1024.0f) - mean * mean;
    const float inv = rsqrtf(var + 1e-5f);
    float4 g = *(const float4*)(gamma + tid * 4);
    float4 bt = *(const float4*)(beta + tid * 4);
    float4 o;
    o.x = g.x * (v.x - mean) * inv + bt.x;
    o.y = g.y * (v.y - mean) * inv + bt.y;
    o.z = g.z * (v.z - mean) * inv + bt.z;
    o.w = g.w * (v.w - mean) * inv + bt.w;
    *(float4*)(out + base) = o;
}

// ---------------- launcher ---------------------------------------------------
extern "C" void kernel_launch(void* const* d_in, const int* in_sizes, int n_in,
                              void* d_out, int out_size, void* d_ws, size_t ws_size,
                              hipStream_t stream)
{
    (void)in_sizes; (void)n_in; (void)out_size; (void)ws_size;
    const float* x       = (const float*)d_in[0];
    const float* qmask   = (const float*)d_in[1];
    const int*   dia_len = (const int*)d_in[2];
    const float* W_msg   = (const float*)d_in[5];
    const float* b_msg   = (const float*)d_in[6];
    const float* W_self  = (const float*)d_in[7];
    const float* b_self  = (const float*)d_in[8];
    const float* W_out   = (const float*)d_in[9];
    const float* b_out   = (const float*)d_in[10];
    const float* gamma   = (const float*)d_in[11];
    const float* beta    = (const float*)d_in[12];
    float* out = (float*)d_out;

    char* ws = (char*)d_ws;
    u16*   xcat   = (u16*)ws;                           // 32 MiB
    u16*   rbuf   = (u16*)(ws + (size_t)(32u << 20));   // 16 MiB
    u16*   wt_cat = (u16*)(ws + (size_t)(48u << 20));   // 4 MiB
    u16*   wt_out = (u16*)(ws + (size_t)(52u << 20));   // 2 MiB
    float* zbuf   = (float*)ws;                         // alias xcat (safe: GEMM2 no longer reads xcat)

    transpose_pack<<<dim3(32, 32, 3), 256, 0, stream>>>(W_self, W_msg, W_out, wt_cat, wt_out);
    msg_pack<<<dim3(64, 8), 256, 0, stream>>>(x, qmask, dia_len, xcat);
    gemm_bt<2048, 1><<<dim3(256), 512, 0, stream>>>(xcat, wt_cat, b_self, b_msg,
                                                    x, dia_len, rbuf, nullptr);
    gemm_bt<1024, 2><<<dim3(256), 512, 0, stream>>>(rbuf, wt_out, b_out, nullptr,
                                                    x, nullptr, nullptr, zbuf);
    ln_kernel<<<dim3(8192), 256, 0, stream>>>(zbuf, gamma, beta, out);
}

// Round 4
// 230.843 us; speedup vs baseline: 1.0436x; 1.0436x over previous
//
#include <hip/hip_runtime.h>

// SimpleDialogGNN on MI355X.
// Pipeline:
//   K0 transpose_pack : W_self,W_msg -> wt_cat (N=1024 x K=2048, bf16, N-major)
//                       W_out        -> wt_out (1024x1024 bf16, N-major)
//   K1 msg_pack       : per-row windowed weighted avg; writes xcat rows
//                       [x_bf16(1024) | msg_bf16(1024)]  (M=8192 x 2048 bf16)
//   K2 gemm<2048,EPI1>: h = xcat @ wt_cat^T + b_self + b_msg;
//                       out = (t<dia_len[b]) ? h : x; r = relu(out) -> bf16
//   K3 gemm<1024,EPI2>: z = x + r @ wt_out^T + b_out -> fp32 zbuf
//   K4 ln_kernel      : LayerNorm(z) * gamma + beta -> d_out (fp32)
//
// GEMM (this round): BM=256, BN=128, BK=64, 512 thr (8 waves, 4Mx2N, 64x64 C
// each), grid 256 = 1 block/CU, 3-deep rotating LDS tiles (144 KiB),
// T2 slot^=(row&7) swizzle (verified: 0 bank conflicts in r3),
// T1 XCD swizzle (verified: FETCH 35.6 MB ~= ideal in r3).
// Sync collapsed to ONE s_barrier + ONE counted s_waitcnt vmcnt(6) per K-tile
// (r3's 9 barriers/tile serialized LDS pipe vs MFMA pipes -> 19% MfmaUtil).
// Within a tile the compiler's fine lgkmcnt interleaves ds_read/MFMA; across
// waves the SIMD scheduler overlaps read-issue with MFMA clusters.
//
// ws layout (bytes): [0,32M) xcat (bf16)  — aliased by zbuf (fp32) after GEMM1
//                    [32M,48M) r (bf16)
//                    [48M,52M) wt_cat     [52M,54M) wt_out
// total ws required: 54 MiB.

typedef unsigned short u16;
typedef float floatx4 __attribute__((ext_vector_type(4)));
typedef short shortx8 __attribute__((ext_vector_type(8)));

#define T_ 1024
#define H_ 1024

__device__ __forceinline__ float bf2f(u16 v) {
    return __uint_as_float(((unsigned)v) << 16);
}
__device__ __forceinline__ u16 f2bf(float f) {  // round-to-nearest-even
    unsigned u = __float_as_uint(f);
    return (u16)((u + 0x7fffu + ((u >> 16) & 1u)) >> 16);
}
__device__ __forceinline__ void async16(const void* g, void* l) {
    __builtin_amdgcn_global_load_lds(
        (__attribute__((address_space(1))) void*)g,
        (__attribute__((address_space(3))) void*)l, 16, 0, 0);
}
__device__ __forceinline__ void barrier_mem() {
    asm volatile("" ::: "memory");
    __builtin_amdgcn_s_barrier();
    asm volatile("" ::: "memory");
}

// ---------------- K0: transpose + fp32->bf16 pack of the three weights ------
__global__ __launch_bounds__(256)
void transpose_pack(const float* __restrict__ Wself, const float* __restrict__ Wmsg,
                    const float* __restrict__ Wout,
                    u16* __restrict__ wt_cat, u16* __restrict__ wt_out)
{
    __shared__ float s[32][33];
    const int wid = blockIdx.z;
    const float* src = (wid == 0) ? Wself : ((wid == 1) ? Wmsg : Wout);
    const int n0 = blockIdx.x * 32, k0 = blockIdx.y * 32;
    const int tx = threadIdx.x & 31, ty = threadIdx.x >> 5;  // 32x8
#pragma unroll
    for (int i = 0; i < 4; ++i) {
        int k = k0 + ty + 8 * i;
        s[ty + 8 * i][tx] = src[(size_t)k * H_ + n0 + tx];
    }
    __syncthreads();
#pragma unroll
    for (int i = 0; i < 4; ++i) {
        int n = n0 + ty + 8 * i;
        u16 v = f2bf(s[tx][ty + 8 * i]);
        if (wid < 2) wt_cat[(size_t)n * 2048 + wid * 1024 + k0 + tx] = v;
        else         wt_out[(size_t)n * 1024 + k0 + tx] = v;
    }
}

// ---------------- K1: message aggregation + bf16 pack ------------------------
__global__ __launch_bounds__(256)
void msg_pack(const float* __restrict__ x, const float* __restrict__ qmask,
              const int* __restrict__ dia_len, u16* __restrict__ xcat)
{
    __shared__ u16 sx[32][1024];  // 64 KiB
    const int tid = threadIdx.x;
    const int b = blockIdx.y;
    const int t0 = blockIdx.x * 16;
    const int dlen = dia_len[b];
    const int c4 = tid * 4;
    const float* xb = x + (size_t)b * T_ * H_;

    unsigned spkmask = 0;
#pragma unroll 4
    for (int r = 0; r < 32; ++r) {
        int row = t0 - 8 + r;
        row = row < 0 ? 0 : (row > T_ - 1 ? T_ - 1 : row);
        const float* q = qmask + ((size_t)b * T_ + row) * 2;
        spkmask |= (q[1] > q[0] ? 1u : 0u) << r;
        float4 v = *(const float4*)(xb + (size_t)row * H_ + c4);
        ushort4 u;
        u.x = f2bf(v.x); u.y = f2bf(v.y); u.z = f2bf(v.z); u.w = f2bf(v.w);
        *(ushort4*)&sx[r][c4] = u;
    }
    __syncthreads();

    for (int lt = 0; lt < 16; ++lt) {
        const int t = t0 + lt;
        const unsigned cs = (spkmask >> (lt + 8)) & 1u;
        float a0 = 0.f, a1 = 0.f, a2 = 0.f, a3 = 0.f;
        int cnt = 0;
#pragma unroll
        for (int o = 0; o < 17; ++o) {
            const int idx = t + o - 8;
            if (idx >= 0 && idx < dlen) {  // block-uniform branch
                const float w = (((spkmask >> (lt + o)) & 1u) == cs) ? 1.0f : 0.5f;
                ++cnt;
                ushort4 u = *(const ushort4*)&sx[lt + o][c4];
                a0 += w * bf2f(u.x); a1 += w * bf2f(u.y);
                a2 += w * bf2f(u.z); a3 += w * bf2f(u.w);
            }
        }
        const float inv = 1.0f / (float)(cnt > 0 ? cnt : 1);
        ushort4 m;
        m.x = f2bf(a0 * inv); m.y = f2bf(a1 * inv);
        m.z = f2bf(a2 * inv); m.w = f2bf(a3 * inv);
        const size_t rowg = (size_t)b * T_ + t;
        *(ushort4*)&xcat[rowg * 2048 + 1024 + c4] = m;
        *(ushort4*)&xcat[rowg * 2048 + c4] = *(const ushort4*)&sx[lt + 8][c4];
    }
}

// ---------------- K2/K3: bf16 MFMA GEMM, 1-barrier-per-tile, BM=256 BN=128 ---
// A: M x K row-major bf16; Bt: N x K row-major bf16 (N-major).
// LDS swizzle (T2): logical (row, 16B-slot s) lives at LDS slot s^(row&7).
// Staged with linear LDS dest + pre-swizzled global source (involution).
template <int K, int EPI>
__global__ __launch_bounds__(512)
void gemm_bt(const u16* __restrict__ A, const u16* __restrict__ Bt,
             const float* __restrict__ bias1, const float* __restrict__ bias2,
             const float* __restrict__ X, const int* __restrict__ dia_len,
             u16* __restrict__ Rout, float* __restrict__ Zout)
{
    constexpr int NT = K / 64;
    static_assert(NT >= 3, "need >=3 K-tiles for depth-2 prefetch");
    __shared__ u16 sA[3][256 * 64];  // 96 KiB
    __shared__ u16 sB[3][128 * 64];  // 48 KiB
    const int tid = threadIdx.x;

    // T1: XCD-aware block swizzle. bid%8 = XCD; each XCD gets 4 contiguous
    // m-panels x all 8 n-tiles so A-panels are fetched once per XCD L2.
    const int bid = blockIdx.x;
    const int li = bid >> 3;                   // 0..31 within XCD
    const int mt = (bid & 7) * 4 + (li >> 3);  // 0..31
    const int nt = li & 7;                     // 0..7
    const int bm = mt * 256, bn = nt * 128;

    const int wave = tid >> 6, lane = tid & 63;
    const int wr = wave >> 1, wc = wave & 1;   // 4M x 2N waves
    const int lrow = lane & 15, lq = lane >> 4;

    // ---- staging (global -> LDS), pre-swizzled source ----
    const int srow = tid >> 3;                 // 0..63 rows per 8KB chunk
    const int sl   = (tid & 7) ^ (srow & 7);   // swizzled 16B slot in row
    const u16* Asrc = A + (size_t)(bm + srow) * K + sl * 8;
    const u16* Bsrc = Bt + (size_t)(bn + srow) * K + sl * 8;

    auto stageA = [&](int t, int buf, int q) {  // q = 0..3 (64-row quarters)
        async16(Asrc + (size_t)q * 64 * K + t * 64,
                &sA[buf][q * 4096 + tid * 8]);
    };
    auto stageB = [&](int t, int buf, int h) {  // h = 0..1 (64-row halves)
        async16(Bsrc + (size_t)h * 64 * K + t * 64,
                &sB[buf][h * 4096 + tid * 8]);
    };

    floatx4 acc[4][4];
#pragma unroll
    for (int i = 0; i < 4; ++i)
#pragma unroll
        for (int j = 0; j < 4; ++j)
            acc[i][j] = (floatx4){0.f, 0.f, 0.f, 0.f};

    // ---- compute-side LDS read offsets (elements) ----
    const int xk = lrow & 7;
    const int paBase = (wr * 64 + lrow) * 64;
    const int pbBase = (wc * 64 + lrow) * 64;
    const int s0 = ((lq) ^ xk) * 8;        // k-half 0 swizzled slot
    const int s1 = ((4 + lq) ^ xk) * 8;    // k-half 1

    // one full K-tile: 16 ds_read_b128 + 6 global_load_lds + 32 MFMA,
    // no internal barriers — compiler emits fine lgkmcnt between read/MFMA.
    auto tile_body = [&](int t, int cur, int stg, bool do_stage) {
        const u16* curA = &sA[cur][0];
        const u16* curB = &sB[cur][0];
        shortx8 a0[4], b0[4], a1[4], b1[4];
#pragma unroll
        for (int j = 0; j < 4; ++j)
            b0[j] = *(const shortx8*)(curB + pbBase + j * 1024 + s0);
#pragma unroll
        for (int i = 0; i < 4; ++i)
            a0[i] = *(const shortx8*)(curA + paBase + i * 1024 + s0);
        if (do_stage) {
            stageA(t + 2, stg, 0); stageA(t + 2, stg, 1);
            stageA(t + 2, stg, 2); stageA(t + 2, stg, 3);
            stageB(t + 2, stg, 0); stageB(t + 2, stg, 1);
        }
#pragma unroll
        for (int j = 0; j < 4; ++j)
            b1[j] = *(const shortx8*)(curB + pbBase + j * 1024 + s1);
#pragma unroll
        for (int i = 0; i < 4; ++i)
            a1[i] = *(const shortx8*)(curA + paBase + i * 1024 + s1);
        __builtin_amdgcn_s_setprio(1);
#pragma unroll
        for (int i = 0; i < 4; ++i)
#pragma unroll
            for (int j = 0; j < 4; ++j)
                acc[i][j] = __builtin_amdgcn_mfma_f32_16x16x32_bf16(
                    a0[i], b0[j], acc[i][j], 0, 0, 0);
#pragma unroll
        for (int i = 0; i < 4; ++i)
#pragma unroll
            for (int j = 0; j < 4; ++j)
                acc[i][j] = __builtin_amdgcn_mfma_f32_16x16x32_bf16(
                    a1[i], b1[j], acc[i][j], 0, 0, 0);
        __builtin_amdgcn_s_setprio(0);
    };

    // ---- prologue: stage tiles 0 and 1 (12 loads/thread in flight) ----
#pragma unroll
    for (int q = 0; q < 4; ++q) stageA(0, 0, q);
    stageB(0, 0, 0); stageB(0, 0, 1);
#pragma unroll
    for (int q = 0; q < 4; ++q) stageA(1, 1, q);
    stageB(1, 1, 0); stageB(1, 1, 1);
    asm volatile("s_waitcnt vmcnt(6)" ::: "memory");  // tile 0 landed
    barrier_mem();

    // ---- main loop: one barrier + one counted vmcnt per K-tile ----
    int cur = 0, stg = 2;
    for (int t = 0; t < NT - 2; ++t) {
        tile_body(t, cur, stg, true);
        // tile t+1's 6 loads retired; tile t+2's 6 stay in flight
        asm volatile("s_waitcnt vmcnt(6)" ::: "memory");
        barrier_mem();
        cur = (cur == 2) ? 0 : cur + 1;
        stg = (stg == 2) ? 0 : stg + 1;
    }
    // tail: tiles NT-2 and NT-1 (no further staging)
    tile_body(NT - 2, cur, stg, false);
    asm volatile("s_waitcnt vmcnt(0)" ::: "memory");  // tile NT-1 landed
    barrier_mem();
    cur = (cur == 2) ? 0 : cur + 1;
    tile_body(NT - 1, cur, stg, false);

    // epilogue — C/D mapping: col = lane&15, row = (lane>>4)*4 + reg
    const int dl = (EPI == 1) ? dia_len[bm >> 10] : 0;  // b uniform (256|1024)
#pragma unroll
    for (int i = 0; i < 4; ++i) {
        const int row0 = bm + wr * 64 + i * 16 + lq * 4;
#pragma unroll
        for (int j = 0; j < 4; ++j) {
            const int col = bn + wc * 64 + j * 16 + lrow;
#pragma unroll
            for (int r = 0; r < 4; ++r) {
                const int row = row0 + r;
                const float v = acc[i][j][r];
                if (EPI == 1) {
                    const float h = v + bias1[col] + bias2[col];
                    float outv;
                    if ((row & (T_ - 1)) < dl) {
                        outv = h;  // majority path: no X read
                    } else {
                        outv = X[(size_t)row * H_ + col];
                    }
                    Rout[(size_t)row * H_ + col] = f2bf(fmaxf(outv, 0.f));
                } else {
                    const float z = X[(size_t)row * H_ + col] + v + bias1[col];
                    Zout[(size_t)row * H_ + col] = z;
                }
            }
        }
    }
}

// ---------------- K4: LayerNorm ---------------------------------------------
__global__ __launch_bounds__(256)
void ln_kernel(const float* __restrict__ Z, const float* __restrict__ gamma,
               const float* __restrict__ beta, float* __restrict__ out)
{
    const int row = blockIdx.x;
    const int tid = threadIdx.x;
    const size_t base = (size_t)row * H_ + tid * 4;
    float4 v = *(const float4*)(Z + base);
    float s = v.x + v.y + v.z + v.w;
    float q = v.x * v.x + v.y * v.y + v.z * v.z + v.w * v.w;
#pragma unroll
    for (int off = 32; off > 0; off >>= 1) {
        s += __shfl_down(s, off);
        q += __shfl_down(q, off);
    }
    __shared__ float ps[4], pq[4];
    const int wave = tid >> 6, lane = tid & 63;
    if (lane == 0) { ps[wave] = s; pq[wave] = q; }
    __syncthreads();
    const float S = ps[0] + ps[1] + ps[2] + ps[3];
    const float Q = pq[0] + pq[1] + pq[2] + pq[3];
    const float mean = S * (1.0f / 1024.0f);
    const float var = Q * (1.0f / 1024.0f) - mean * mean;
    const float inv = rsqrtf(var + 1e-5f);
    float4 g = *(const float4*)(gamma + tid * 4);
    float4 bt = *(const float4*)(beta + tid * 4);
    float4 o;
    o.x = g.x * (v.x - mean) * inv + bt.x;
    o.y = g.y * (v.y - mean) * inv + bt.y;
    o.z = g.z * (v.z - mean) * inv + bt.z;
    o.w = g.w * (v.w - mean) * inv + bt.w;
    *(float4*)(out + base) = o;
}

// ---------------- launcher ---------------------------------------------------
extern "C" void kernel_launch(void* const* d_in, const int* in_sizes, int n_in,
                              void* d_out, int out_size, void* d_ws, size_t ws_size,
                              hipStream_t stream)
{
    (void)in_sizes; (void)n_in; (void)out_size; (void)ws_size;
    const float* x       = (const float*)d_in[0];
    const float* qmask   = (const float*)d_in[1];
    const int*   dia_len = (const int*)d_in[2];
    const float* W_msg   = (const float*)d_in[5];
    const float* b_msg   = (const float*)d_in[6];
    const float* W_self  = (const float*)d_in[7];
    const float* b_self  = (const float*)d_in[8];
    const float* W_out   = (const float*)d_in[9];
    const float* b_out   = (const float*)d_in[10];
    const float* gamma   = (const float*)d_in[11];
    const float* beta    = (const float*)d_in[12];
    float* out = (float*)d_out;

    char* ws = (char*)d_ws;
    u16*   xcat   = (u16*)ws;                           // 32 MiB
    u16*   rbuf   = (u16*)(ws + (size_t)(32u << 20));   // 16 MiB
    u16*   wt_cat = (u16*)(ws + (size_t)(48u << 20));   // 4 MiB
    u16*   wt_out = (u16*)(ws + (size_t)(52u << 20));   // 2 MiB
    float* zbuf   = (float*)ws;                         // alias xcat (safe: GEMM2 no longer reads xcat)

    transpose_pack<<<dim3(32, 32, 3), 256, 0, stream>>>(W_self, W_msg, W_out, wt_cat, wt_out);
    msg_pack<<<dim3(64, 8), 256, 0, stream>>>(x, qmask, dia_len, xcat);
    gemm_bt<2048, 1><<<dim3(256), 512, 0, stream>>>(xcat, wt_cat, b_self, b_msg,
                                                    x, dia_len, rbuf, nullptr);
    gemm_bt<1024, 2><<<dim3(256), 512, 0, stream>>>(rbuf, wt_out, b_out, nullptr,
                                                    x, nullptr, nullptr, zbuf);
    ln_kernel<<<dim3(8192), 256, 0, stream>>>(zbuf, gamma, beta, out);
}

// Round 5
// 223.145 us; speedup vs baseline: 1.0796x; 1.0345x over previous
//
#include <hip/hip_runtime.h>

// SimpleDialogGNN on MI355X.
// Pipeline:
//   K0 transpose_pack : W_self,W_msg -> wt_cat (N=1024 x K=2048, bf16, N-major)
//                       W_out        -> wt_out (1024x1024 bf16, N-major)
//   K1 msg_pack       : per-row windowed weighted avg; writes xcat rows
//                       [x_bf16(1024) | msg_bf16(1024)]  (M=8192 x 2048 bf16)
//   K2 gemm<2048,EPI1>: h = xcat @ wt_cat^T + b_self + b_msg;
//                       out = (t<dia_len[b]) ? h : x; r = relu(out) -> bf16
//   K3 gemm<1024,EPI2>: z = x + r @ wt_out^T + b_out -> fp32 zbuf
//   K4 ln_kernel      : LayerNorm(z) * gamma + beta -> d_out (fp32)
//
// GEMM (this round): fuse the two proven wins:
//   - r0's occupancy: 128x128 tile, 256 thr, 4 waves, grid 512 = 2 blocks/CU
//     (2 independent blocks hide each other's stalls — r0 56.5us beat every
//      1-block/CU schedule at 66-67us).
//   - r3/r4's memory machinery: BK=64, T2 slot^=(row&7) swizzle (0 bank
//     conflicts verified), XCD block map (FETCH ~ideal verified), 2-slot
//     double buffer with stage(t+1) issued at TOP of body t so the single
//     vmcnt(0) at body end waits on ~1-body-old loads (cheap).
//   LDS 64 KiB/block -> both blocks resident. One barrier per K-tile.
//
// ws layout (bytes): [0,32M) xcat (bf16)  — aliased by zbuf (fp32) after GEMM1
//                    [32M,48M) r (bf16)
//                    [48M,52M) wt_cat     [52M,54M) wt_out
// total ws required: 54 MiB.

typedef unsigned short u16;
typedef float floatx4 __attribute__((ext_vector_type(4)));
typedef short shortx8 __attribute__((ext_vector_type(8)));

#define T_ 1024
#define H_ 1024

__device__ __forceinline__ float bf2f(u16 v) {
    return __uint_as_float(((unsigned)v) << 16);
}
__device__ __forceinline__ u16 f2bf(float f) {  // round-to-nearest-even
    unsigned u = __float_as_uint(f);
    return (u16)((u + 0x7fffu + ((u >> 16) & 1u)) >> 16);
}
__device__ __forceinline__ void async16(const void* g, void* l) {
    __builtin_amdgcn_global_load_lds(
        (__attribute__((address_space(1))) void*)g,
        (__attribute__((address_space(3))) void*)l, 16, 0, 0);
}
__device__ __forceinline__ void barrier_mem() {
    asm volatile("" ::: "memory");
    __builtin_amdgcn_s_barrier();
    asm volatile("" ::: "memory");
}

// ---------------- K0: transpose + fp32->bf16 pack of the three weights ------
__global__ __launch_bounds__(256)
void transpose_pack(const float* __restrict__ Wself, const float* __restrict__ Wmsg,
                    const float* __restrict__ Wout,
                    u16* __restrict__ wt_cat, u16* __restrict__ wt_out)
{
    __shared__ float s[32][33];
    const int wid = blockIdx.z;
    const float* src = (wid == 0) ? Wself : ((wid == 1) ? Wmsg : Wout);
    const int n0 = blockIdx.x * 32, k0 = blockIdx.y * 32;
    const int tx = threadIdx.x & 31, ty = threadIdx.x >> 5;  // 32x8
#pragma unroll
    for (int i = 0; i < 4; ++i) {
        int k = k0 + ty + 8 * i;
        s[ty + 8 * i][tx] = src[(size_t)k * H_ + n0 + tx];
    }
    __syncthreads();
#pragma unroll
    for (int i = 0; i < 4; ++i) {
        int n = n0 + ty + 8 * i;
        u16 v = f2bf(s[tx][ty + 8 * i]);
        if (wid < 2) wt_cat[(size_t)n * 2048 + wid * 1024 + k0 + tx] = v;
        else         wt_out[(size_t)n * 1024 + k0 + tx] = v;
    }
}

// ---------------- K1: message aggregation + bf16 pack ------------------------
__global__ __launch_bounds__(256)
void msg_pack(const float* __restrict__ x, const float* __restrict__ qmask,
              const int* __restrict__ dia_len, u16* __restrict__ xcat)
{
    __shared__ u16 sx[32][1024];  // 64 KiB
    const int tid = threadIdx.x;
    const int b = blockIdx.y;
    const int t0 = blockIdx.x * 16;
    const int dlen = dia_len[b];
    const int c4 = tid * 4;
    const float* xb = x + (size_t)b * T_ * H_;

    unsigned spkmask = 0;
#pragma unroll 4
    for (int r = 0; r < 32; ++r) {
        int row = t0 - 8 + r;
        row = row < 0 ? 0 : (row > T_ - 1 ? T_ - 1 : row);
        const float* q = qmask + ((size_t)b * T_ + row) * 2;
        spkmask |= (q[1] > q[0] ? 1u : 0u) << r;
        float4 v = *(const float4*)(xb + (size_t)row * H_ + c4);
        ushort4 u;
        u.x = f2bf(v.x); u.y = f2bf(v.y); u.z = f2bf(v.z); u.w = f2bf(v.w);
        *(ushort4*)&sx[r][c4] = u;
    }
    __syncthreads();

    for (int lt = 0; lt < 16; ++lt) {
        const int t = t0 + lt;
        const unsigned cs = (spkmask >> (lt + 8)) & 1u;
        float a0 = 0.f, a1 = 0.f, a2 = 0.f, a3 = 0.f;
        int cnt = 0;
#pragma unroll
        for (int o = 0; o < 17; ++o) {
            const int idx = t + o - 8;
            if (idx >= 0 && idx < dlen) {  // block-uniform branch
                const float w = (((spkmask >> (lt + o)) & 1u) == cs) ? 1.0f : 0.5f;
                ++cnt;
                ushort4 u = *(const ushort4*)&sx[lt + o][c4];
                a0 += w * bf2f(u.x); a1 += w * bf2f(u.y);
                a2 += w * bf2f(u.z); a3 += w * bf2f(u.w);
            }
        }
        const float inv = 1.0f / (float)(cnt > 0 ? cnt : 1);
        ushort4 m;
        m.x = f2bf(a0 * inv); m.y = f2bf(a1 * inv);
        m.z = f2bf(a2 * inv); m.w = f2bf(a3 * inv);
        const size_t rowg = (size_t)b * T_ + t;
        *(ushort4*)&xcat[rowg * 2048 + 1024 + c4] = m;
        *(ushort4*)&xcat[rowg * 2048 + c4] = *(const ushort4*)&sx[lt + 8][c4];
    }
}

// ---------------- K2/K3: bf16 MFMA GEMM, 128x128, BK=64, 2-slot dbuf ---------
// A: M x K row-major bf16; Bt: N x K row-major bf16 (N-major).
// LDS swizzle (T2): logical (row, 16B-slot s) lives at LDS slot s^(row&7).
// Staged with linear LDS dest + pre-swizzled global source (involution).
template <int K, int EPI>
__global__ __launch_bounds__(256, 2)
void gemm_bt(const u16* __restrict__ A, const u16* __restrict__ Bt,
             const float* __restrict__ bias1, const float* __restrict__ bias2,
             const float* __restrict__ X, const int* __restrict__ dia_len,
             u16* __restrict__ Rout, float* __restrict__ Zout)
{
    constexpr int NT = K / 64;
    static_assert(NT >= 2, "need >=2 K-tiles");
    __shared__ u16 sA[2][128 * 64];  // 32 KiB
    __shared__ u16 sB[2][128 * 64];  // 32 KiB
    const int tid = threadIdx.x;

    // T1: XCD-aware block map. bid%8 = XCD; each XCD gets 8 contiguous
    // m-tiles x all 8 n-tiles -> per-XCD working set: A panel 1024 rows +
    // full B, mostly L2/L3-resident (verified ~ideal FETCH in r3/r4).
    const int bid = blockIdx.x;
    const int xcd = bid & 7, li = bid >> 3;     // li in [0,64)
    const int mt = xcd * 8 + (li >> 3);         // 0..63
    const int nt = li & 7;                      // 0..7
    const int bm = mt * 128, bn = nt * 128;

    const int wave = tid >> 6, lane = tid & 63;
    const int wr = wave >> 1, wc = wave & 1;    // 2M x 2N waves, 64x64 C each
    const int lrow = lane & 15, lq = lane >> 4;

    // ---- staging (global -> LDS), pre-swizzled source ----
    // 256 thr x 16B = 4 KiB = 32 rows x 128B per chunk; 4 chunks per tile.
    const int srow = tid >> 3;                  // 0..31
    const int sl   = (tid & 7) ^ (srow & 7);    // swizzled 16B slot in row
    const u16* Asrc = A + (size_t)(bm + srow) * K + sl * 8;
    const u16* Bsrc = Bt + (size_t)(bn + srow) * K + sl * 8;

    auto stage = [&](int t, int buf) {          // 8 async16 per thread
        const int k0 = t * 64;
#pragma unroll
        for (int q = 0; q < 4; ++q)
            async16(Asrc + (size_t)q * 32 * K + k0, &sA[buf][q * 2048 + tid * 8]);
#pragma unroll
        for (int q = 0; q < 4; ++q)
            async16(Bsrc + (size_t)q * 32 * K + k0, &sB[buf][q * 2048 + tid * 8]);
    };

    floatx4 acc[4][4];
#pragma unroll
    for (int i = 0; i < 4; ++i)
#pragma unroll
        for (int j = 0; j < 4; ++j)
            acc[i][j] = (floatx4){0.f, 0.f, 0.f, 0.f};

    // ---- compute-side LDS read offsets (elements) ----
    const int xk = lrow & 7;
    const int paBase = (wr * 64 + lrow) * 64;
    const int pbBase = (wc * 64 + lrow) * 64;
    const int s0 = (lq ^ xk) * 8;               // k-half 0 swizzled slot
    const int s1 = ((4 + lq) ^ xk) * 8;         // k-half 1

    // ---- prologue: both slots in flight; wait tile 0 only ----
    stage(0, 0);
    stage(1, 1);
    asm volatile("s_waitcnt vmcnt(8)" ::: "memory");  // tile 0 landed
    barrier_mem();

    for (int t = 0; t < NT; ++t) {
        // stage tile t+1's successor's slot is busy; with 2 slots we stage
        // t+1 only from t>=1 (t=0's next tile was staged in the prologue).
        if (t >= 1 && t + 1 < NT) stage(t + 1, (t + 1) & 1);

        const u16* curA = &sA[t & 1][0];
        const u16* curB = &sB[t & 1][0];
        shortx8 a0[4], b0[4], a1[4], b1[4];
#pragma unroll
        for (int j = 0; j < 4; ++j)
            b0[j] = *(const shortx8*)(curB + pbBase + j * 1024 + s0);
#pragma unroll
        for (int i = 0; i < 4; ++i)
            a0[i] = *(const shortx8*)(curA + paBase + i * 1024 + s0);
#pragma unroll
        for (int j = 0; j < 4; ++j)
            b1[j] = *(const shortx8*)(curB + pbBase + j * 1024 + s1);
#pragma unroll
        for (int i = 0; i < 4; ++i)
            a1[i] = *(const shortx8*)(curA + paBase + i * 1024 + s1);

        __builtin_amdgcn_s_setprio(1);
#pragma unroll
        for (int i = 0; i < 4; ++i)
#pragma unroll
            for (int j = 0; j < 4; ++j)
                acc[i][j] = __builtin_amdgcn_mfma_f32_16x16x32_bf16(
                    a0[i], b0[j], acc[i][j], 0, 0, 0);
#pragma unroll
        for (int i = 0; i < 4; ++i)
#pragma unroll
            for (int j = 0; j < 4; ++j)
                acc[i][j] = __builtin_amdgcn_mfma_f32_16x16x32_bf16(
                    a1[i], b1[j], acc[i][j], 0, 0, 0);
        __builtin_amdgcn_s_setprio(0);

        if (t + 1 < NT) {
            // tile t+1's 8 loads were issued >= one body ago — cheap wait.
            asm volatile("s_waitcnt vmcnt(0)" ::: "memory");
            barrier_mem();  // also WAR-protects the next stage()
        }
    }

    // epilogue — C/D mapping: col = lane&15, row = (lane>>4)*4 + reg
    const int dl = (EPI == 1) ? dia_len[bm >> 10] : 0;  // b uniform (128|1024)
#pragma unroll
    for (int i = 0; i < 4; ++i) {
        const int row0 = bm + wr * 64 + i * 16 + lq * 4;
#pragma unroll
        for (int j = 0; j < 4; ++j) {
            const int col = bn + wc * 64 + j * 16 + lrow;
#pragma unroll
            for (int r = 0; r < 4; ++r) {
                const int row = row0 + r;
                const float v = acc[i][j][r];
                if (EPI == 1) {
                    const float h = v + bias1[col] + bias2[col];
                    float outv;
                    if ((row & (T_ - 1)) < dl) {
                        outv = h;  // majority path: no X read
                    } else {
                        outv = X[(size_t)row * H_ + col];
                    }
                    Rout[(size_t)row * H_ + col] = f2bf(fmaxf(outv, 0.f));
                } else {
                    const float z = X[(size_t)row * H_ + col] + v + bias1[col];
                    Zout[(size_t)row * H_ + col] = z;
                }
            }
        }
    }
}

// ---------------- K4: LayerNorm ---------------------------------------------
__global__ __launch_bounds__(256)
void ln_kernel(const float* __restrict__ Z, const float* __restrict__ gamma,
               const float* __restrict__ beta, float* __restrict__ out)
{
    const int row = blockIdx.x;
    const int tid = threadIdx.x;
    const size_t base = (size_t)row * H_ + tid * 4;
    float4 v = *(const float4*)(Z + base);
    float s = v.x + v.y + v.z + v.w;
    float q = v.x * v.x + v.y * v.y + v.z * v.z + v.w * v.w;
#pragma unroll
    for (int off = 32; off > 0; off >>= 1) {
        s += __shfl_down(s, off);
        q += __shfl_down(q, off);
    }
    __shared__ float ps[4], pq[4];
    const int wave = tid >> 6, lane = tid & 63;
    if (lane == 0) { ps[wave] = s; pq[wave] = q; }
    __syncthreads();
    const float S = ps[0] + ps[1] + ps[2] + ps[3];
    const float Q = pq[0] + pq[1] + pq[2] + pq[3];
    const float mean = S * (1.0f / 1024.0f);
    const float var = Q * (1.0f / 1024.0f) - mean * mean;
    const float inv = rsqrtf(var + 1e-5f);
    float4 g = *(const float4*)(gamma + tid * 4);
    float4 bt = *(const float4*)(beta + tid * 4);
    float4 o;
    o.x = g.x * (v.x - mean) * inv + bt.x;
    o.y = g.y * (v.y - mean) * inv + bt.y;
    o.z = g.z * (v.z - mean) * inv + bt.z;
    o.w = g.w * (v.w - mean) * inv + bt.w;
    *(float4*)(out + base) = o;
}

// ---------------- launcher ---------------------------------------------------
extern "C" void kernel_launch(void* const* d_in, const int* in_sizes, int n_in,
                              void* d_out, int out_size, void* d_ws, size_t ws_size,
                              hipStream_t stream)
{
    (void)in_sizes; (void)n_in; (void)out_size; (void)ws_size;
    const float* x       = (const float*)d_in[0];
    const float* qmask   = (const float*)d_in[1];
    const int*   dia_len = (const int*)d_in[2];
    const float* W_msg   = (const float*)d_in[5];
    const float* b_msg   = (const float*)d_in[6];
    const float* W_self  = (const float*)d_in[7];
    const float* b_self  = (const float*)d_in[8];
    const float* W_out   = (const float*)d_in[9];
    const float* b_out   = (const float*)d_in[10];
    const float* gamma   = (const float*)d_in[11];
    const float* beta    = (const float*)d_in[12];
    float* out = (float*)d_out;

    char* ws = (char*)d_ws;
    u16*   xcat   = (u16*)ws;                           // 32 MiB
    u16*   rbuf   = (u16*)(ws + (size_t)(32u << 20));   // 16 MiB
    u16*   wt_cat = (u16*)(ws + (size_t)(48u << 20));   // 4 MiB
    u16*   wt_out = (u16*)(ws + (size_t)(52u << 20));   // 2 MiB
    float* zbuf   = (float*)ws;                         // alias xcat (safe: GEMM2 no longer reads xcat)

    transpose_pack<<<dim3(32, 32, 3), 256, 0, stream>>>(W_self, W_msg, W_out, wt_cat, wt_out);
    msg_pack<<<dim3(64, 8), 256, 0, stream>>>(x, qmask, dia_len, xcat);
    gemm_bt<2048, 1><<<dim3(512), 256, 0, stream>>>(xcat, wt_cat, b_self, b_msg,
                                                    x, dia_len, rbuf, nullptr);
    gemm_bt<1024, 2><<<dim3(512), 256, 0, stream>>>(rbuf, wt_out, b_out, nullptr,
                                                    x, nullptr, nullptr, zbuf);
    ln_kernel<<<dim3(8192), 256, 0, stream>>>(zbuf, gamma, beta, out);
}

// Round 6
// 206.409 us; speedup vs baseline: 1.1672x; 1.0811x over previous
//
#include <hip/hip_runtime.h>

// SimpleDialogGNN on MI355X.
// Pipeline (4 launches):
//   K0 prep_kernel    : fused {transpose_pack + msg_pack}
//                       - W_self,W_msg -> wt_cat (1024x2048 bf16, N-major),
//                         W_out -> wt_out (1024x1024 bf16, N-major)
//                       - windowed weighted avg -> xcat rows
//                         [x_bf16(1024) | msg_bf16(1024)] (8192 x 2048 bf16)
//   K1 gemm<2048,EPI1>: h = xcat @ wt_cat^T + b_self + b_msg;
//                       out = (t<dia_len[b]) ? h : x; r = relu(out) -> bf16
//   K2 gemm<1024,EPI2>: z = x + r @ wt_out^T + b_out -> fp32 zbuf
//   K3 ln_kernel      : LayerNorm(z) * gamma + beta -> d_out (fp32)
//
// GEMM core (this round): same verified memory machinery as r5 (BK=64,
// 2-slot dbuf, T2 slot^=(row&7) swizzle -> 0 bank conflicts, XCD map ->
// FETCH ~ideal, stage-at-top + single vmcnt(0)+barrier per tile), but
// 512 threads / 8 waves per block (4Mx2N, 32x64 C per wave, acc[2][4]).
// Rationale: r0/r4/r5 all stall ~35% of CU cycles at 2 waves/SIMD
// regardless of schedule; 8 waves/block doubles to 4 waves/SIMD with the
// same 64 KiB LDS (2 blocks/CU). LDS-pipe floor rises to ~31us (ratio
// 0.75 ds_read/MFMA) but TLP should finally hide the load-return latency.
//
// ws layout (bytes): [0,32M) xcat (bf16)  — aliased by zbuf (fp32) after GEMM1
//                    [32M,48M) r (bf16)
//                    [48M,52M) wt_cat     [52M,54M) wt_out
// total ws required: 54 MiB.

typedef unsigned short u16;
typedef float floatx4 __attribute__((ext_vector_type(4)));
typedef short shortx8 __attribute__((ext_vector_type(8)));

#define T_ 1024
#define H_ 1024

__device__ __forceinline__ float bf2f(u16 v) {
    return __uint_as_float(((unsigned)v) << 16);
}
__device__ __forceinline__ u16 f2bf(float f) {  // round-to-nearest-even
    unsigned u = __float_as_uint(f);
    return (u16)((u + 0x7fffu + ((u >> 16) & 1u)) >> 16);
}
__device__ __forceinline__ void async16(const void* g, void* l) {
    __builtin_amdgcn_global_load_lds(
        (__attribute__((address_space(1))) void*)g,
        (__attribute__((address_space(3))) void*)l, 16, 0, 0);
}
__device__ __forceinline__ void barrier_mem() {
    asm volatile("" ::: "memory");
    __builtin_amdgcn_s_barrier();
    asm volatile("" ::: "memory");
}

// ---------------- K0: fused weight-pack + message aggregation ----------------
// blocks [0,512): msg_pack work (b = bx>>6, t-chunk = bx&63)
// blocks [512,3584): transpose_pack work (id -> wid, n0, k0)
__global__ __launch_bounds__(256)
void prep_kernel(const float* __restrict__ x, const float* __restrict__ qmask,
                 const int* __restrict__ dia_len,
                 const float* __restrict__ Wself, const float* __restrict__ Wmsg,
                 const float* __restrict__ Wout,
                 u16* __restrict__ xcat, u16* __restrict__ wt_cat,
                 u16* __restrict__ wt_out)
{
    __shared__ u16 sx[32][1024];  // 64 KiB (transpose path reuses a corner)
    const int tid = threadIdx.x;
    const int bx = blockIdx.x;

    if (bx >= 512) {
        // ---- transpose + bf16 pack of one 32x32 weight tile ----
        const int id = bx - 512;            // 0..3071
        const int wid = id >> 10;           // 0..2
        const int rest = id & 1023;
        const int n0 = (rest & 31) * 32, k0 = (rest >> 5) * 32;
        const float* src = (wid == 0) ? Wself : ((wid == 1) ? Wmsg : Wout);
        float (*s)[33] = reinterpret_cast<float (*)[33]>(&sx[0][0]);
        const int tx = tid & 31, ty = tid >> 5;  // 32x8
#pragma unroll
        for (int i = 0; i < 4; ++i) {
            int k = k0 + ty + 8 * i;
            s[ty + 8 * i][tx] = src[(size_t)k * H_ + n0 + tx];
        }
        __syncthreads();
#pragma unroll
        for (int i = 0; i < 4; ++i) {
            int n = n0 + ty + 8 * i;
            u16 v = f2bf(s[tx][ty + 8 * i]);
            if (wid < 2) wt_cat[(size_t)n * 2048 + wid * 1024 + k0 + tx] = v;
            else         wt_out[(size_t)n * 1024 + k0 + tx] = v;
        }
        return;
    }

    // ---- msg_pack: stage 32 rows (halo 8 each side) as bf16 in LDS ----
    const int b = bx >> 6;
    const int t0 = (bx & 63) * 16;
    const int dlen = dia_len[b];
    const int c4 = tid * 4;
    const float* xb = x + (size_t)b * T_ * H_;

    unsigned spkmask = 0;
#pragma unroll 4
    for (int r = 0; r < 32; ++r) {
        int row = t0 - 8 + r;
        row = row < 0 ? 0 : (row > T_ - 1 ? T_ - 1 : row);
        const float* q = qmask + ((size_t)b * T_ + row) * 2;
        spkmask |= (q[1] > q[0] ? 1u : 0u) << r;
        float4 v = *(const float4*)(xb + (size_t)row * H_ + c4);
        ushort4 u;
        u.x = f2bf(v.x); u.y = f2bf(v.y); u.z = f2bf(v.z); u.w = f2bf(v.w);
        *(ushort4*)&sx[r][c4] = u;
    }
    __syncthreads();

    for (int lt = 0; lt < 16; ++lt) {
        const int t = t0 + lt;
        const unsigned cs = (spkmask >> (lt + 8)) & 1u;
        float a0 = 0.f, a1 = 0.f, a2 = 0.f, a3 = 0.f;
        int cnt = 0;
#pragma unroll
        for (int o = 0; o < 17; ++o) {
            const int idx = t + o - 8;
            if (idx >= 0 && idx < dlen) {  // block-uniform branch
                const float w = (((spkmask >> (lt + o)) & 1u) == cs) ? 1.0f : 0.5f;
                ++cnt;
                ushort4 u = *(const ushort4*)&sx[lt + o][c4];
                a0 += w * bf2f(u.x); a1 += w * bf2f(u.y);
                a2 += w * bf2f(u.z); a3 += w * bf2f(u.w);
            }
        }
        const float inv = 1.0f / (float)(cnt > 0 ? cnt : 1);
        ushort4 m;
        m.x = f2bf(a0 * inv); m.y = f2bf(a1 * inv);
        m.z = f2bf(a2 * inv); m.w = f2bf(a3 * inv);
        const size_t rowg = (size_t)b * T_ + t;
        *(ushort4*)&xcat[rowg * 2048 + 1024 + c4] = m;
        *(ushort4*)&xcat[rowg * 2048 + c4] = *(const ushort4*)&sx[lt + 8][c4];
    }
}

// ---------------- K1/K2: bf16 MFMA GEMM, 128x128, BK=64, 8 waves -------------
// A: M x K row-major bf16; Bt: N x K row-major bf16 (N-major).
// LDS swizzle (T2): logical (row, 16B-slot s) lives at LDS slot s^(row&7).
// Staged with linear LDS dest + pre-swizzled global source (involution).
template <int K, int EPI>
__global__ __launch_bounds__(512, 4)
void gemm_bt(const u16* __restrict__ A, const u16* __restrict__ Bt,
             const float* __restrict__ bias1, const float* __restrict__ bias2,
             const float* __restrict__ X, const int* __restrict__ dia_len,
             u16* __restrict__ Rout, float* __restrict__ Zout)
{
    constexpr int NT = K / 64;
    static_assert(NT >= 2, "need >=2 K-tiles");
    __shared__ u16 sA[2][128 * 64];  // 32 KiB
    __shared__ u16 sB[2][128 * 64];  // 32 KiB
    const int tid = threadIdx.x;

    // T1: XCD-aware block map (verified ~ideal FETCH in r3-r5).
    const int bid = blockIdx.x;
    const int xcd = bid & 7, li = bid >> 3;     // li in [0,64)
    const int mt = xcd * 8 + (li >> 3);         // 0..63
    const int nt = li & 7;                      // 0..7
    const int bm = mt * 128, bn = nt * 128;

    const int wave = tid >> 6, lane = tid & 63;
    const int wr = wave >> 1, wc = wave & 1;    // 4M x 2N waves, 32x64 C each
    const int lrow = lane & 15, lq = lane >> 4;

    // ---- staging (global -> LDS), pre-swizzled source ----
    // 512 thr x 16B = 8 KiB = 64 rows x 128B per pass; 2 passes per operand.
    const int srow = tid >> 3;                  // 0..63
    const int sl   = (tid & 7) ^ (srow & 7);    // swizzled 16B slot in row
    const u16* Asrc = A + (size_t)(bm + srow) * K + sl * 8;
    const u16* Bsrc = Bt + (size_t)(bn + srow) * K + sl * 8;

    auto stage = [&](int t, int buf) {          // 4 async16 per thread
        const int k0 = t * 64;
        async16(Asrc + k0,                    &sA[buf][tid * 8]);
        async16(Asrc + (size_t)64 * K + k0,   &sA[buf][4096 + tid * 8]);
        async16(Bsrc + k0,                    &sB[buf][tid * 8]);
        async16(Bsrc + (size_t)64 * K + k0,   &sB[buf][4096 + tid * 8]);
    };

    floatx4 acc[2][4];
#pragma unroll
    for (int i = 0; i < 2; ++i)
#pragma unroll
        for (int j = 0; j < 4; ++j)
            acc[i][j] = (floatx4){0.f, 0.f, 0.f, 0.f};

    // ---- compute-side LDS read offsets (elements) ----
    const int xk = lrow & 7;
    const int paBase = (wr * 32 + lrow) * 64;
    const int pbBase = (wc * 64 + lrow) * 64;
    const int s0 = (lq ^ xk) * 8;               // k-half 0 swizzled slot
    const int s1 = ((4 + lq) ^ xk) * 8;         // k-half 1

    // ---- prologue: both slots in flight; wait tile 0 only ----
    stage(0, 0);
    stage(1, 1);
    asm volatile("s_waitcnt vmcnt(4)" ::: "memory");  // tile 0 landed
    barrier_mem();

    for (int t = 0; t < NT; ++t) {
        if (t >= 1 && t + 1 < NT) stage(t + 1, (t + 1) & 1);

        const u16* curA = &sA[t & 1][0];
        const u16* curB = &sB[t & 1][0];
        shortx8 a0[2], a1[2], b0[4], b1[4];
#pragma unroll
        for (int j = 0; j < 4; ++j)
            b0[j] = *(const shortx8*)(curB + pbBase + j * 1024 + s0);
#pragma unroll
        for (int i = 0; i < 2; ++i)
            a0[i] = *(const shortx8*)(curA + paBase + i * 1024 + s0);
#pragma unroll
        for (int j = 0; j < 4; ++j)
            b1[j] = *(const shortx8*)(curB + pbBase + j * 1024 + s1);
#pragma unroll
        for (int i = 0; i < 2; ++i)
            a1[i] = *(const shortx8*)(curA + paBase + i * 1024 + s1);

        __builtin_amdgcn_s_setprio(1);
#pragma unroll
        for (int i = 0; i < 2; ++i)
#pragma unroll
            for (int j = 0; j < 4; ++j)
                acc[i][j] = __builtin_amdgcn_mfma_f32_16x16x32_bf16(
                    a0[i], b0[j], acc[i][j], 0, 0, 0);
#pragma unroll
        for (int i = 0; i < 2; ++i)
#pragma unroll
            for (int j = 0; j < 4; ++j)
                acc[i][j] = __builtin_amdgcn_mfma_f32_16x16x32_bf16(
                    a1[i], b1[j], acc[i][j], 0, 0, 0);
        __builtin_amdgcn_s_setprio(0);

        if (t + 1 < NT) {
            // drain stage(t+1) (issued at top of this body) so slot is ready
            asm volatile("s_waitcnt vmcnt(0)" ::: "memory");
            barrier_mem();  // also WAR-protects the next stage()
        }
    }

    // epilogue — C/D mapping: col = lane&15, row = (lane>>4)*4 + reg
    const int dl = (EPI == 1) ? dia_len[bm >> 10] : 0;  // b uniform per block
#pragma unroll
    for (int i = 0; i < 2; ++i) {
        const int row0 = bm + wr * 32 + i * 16 + lq * 4;
#pragma unroll
        for (int j = 0; j < 4; ++j) {
            const int col = bn + wc * 64 + j * 16 + lrow;
#pragma unroll
            for (int r = 0; r < 4; ++r) {
                const int row = row0 + r;
                const float v = acc[i][j][r];
                if (EPI == 1) {
                    const float h = v + bias1[col] + bias2[col];
                    float outv;
                    if ((row & (T_ - 1)) < dl) {
                        outv = h;  // majority path: no X read
                    } else {
                        outv = X[(size_t)row * H_ + col];
                    }
                    Rout[(size_t)row * H_ + col] = f2bf(fmaxf(outv, 0.f));
                } else {
                    const float z = X[(size_t)row * H_ + col] + v + bias1[col];
                    Zout[(size_t)row * H_ + col] = z;
                }
            }
        }
    }
}

// ---------------- K3: LayerNorm ---------------------------------------------
__global__ __launch_bounds__(256)
void ln_kernel(const float* __restrict__ Z, const float* __restrict__ gamma,
               const float* __restrict__ beta, float* __restrict__ out)
{
    const int row = blockIdx.x;
    const int tid = threadIdx.x;
    const size_t base = (size_t)row * H_ + tid * 4;
    float4 v = *(const float4*)(Z + base);
    float s = v.x + v.y + v.z + v.w;
    float q = v.x * v.x + v.y * v.y + v.z * v.z + v.w * v.w;
#pragma unroll
    for (int off = 32; off > 0; off >>= 1) {
        s += __shfl_down(s, off);
        q += __shfl_down(q, off);
    }
    __shared__ float ps[4], pq[4];
    const int wave = tid >> 6, lane = tid & 63;
    if (lane == 0) { ps[wave] = s; pq[wave] = q; }
    __syncthreads();
    const float S = ps[0] + ps[1] + ps[2] + ps[3];
    const float Q = pq[0] + pq[1] + pq[2] + pq[3];
    const float mean = S * (1.0f / 1024.0f);
    const float var = Q * (1.0f / 1024.0f) - mean * mean;
    const float inv = rsqrtf(var + 1e-5f);
    float4 g = *(const float4*)(gamma + tid * 4);
    float4 bt = *(const float4*)(beta + tid * 4);
    float4 o;
    o.x = g.x * (v.x - mean) * inv + bt.x;
    o.y = g.y * (v.y - mean) * inv + bt.y;
    o.z = g.z * (v.z - mean) * inv + bt.z;
    o.w = g.w * (v.w - mean) * inv + bt.w;
    *(float4*)(out + base) = o;
}

// ---------------- launcher ---------------------------------------------------
extern "C" void kernel_launch(void* const* d_in, const int* in_sizes, int n_in,
                              void* d_out, int out_size, void* d_ws, size_t ws_size,
                              hipStream_t stream)
{
    (void)in_sizes; (void)n_in; (void)out_size; (void)ws_size;
    const float* x       = (const float*)d_in[0];
    const float* qmask   = (const float*)d_in[1];
    const int*   dia_len = (const int*)d_in[2];
    const float* W_msg   = (const float*)d_in[5];
    const float* b_msg   = (const float*)d_in[6];
    const float* W_self  = (const float*)d_in[7];
    const float* b_self  = (const float*)d_in[8];
    const float* W_out   = (const float*)d_in[9];
    const float* b_out   = (const float*)d_in[10];
    const float* gamma   = (const float*)d_in[11];
    const float* beta    = (const float*)d_in[12];
    float* out = (float*)d_out;

    char* ws = (char*)d_ws;
    u16*   xcat   = (u16*)ws;                           // 32 MiB
    u16*   rbuf   = (u16*)(ws + (size_t)(32u << 20));   // 16 MiB
    u16*   wt_cat = (u16*)(ws + (size_t)(48u << 20));   // 4 MiB
    u16*   wt_out = (u16*)(ws + (size_t)(52u << 20));   // 2 MiB
    float* zbuf   = (float*)ws;                         // alias xcat (safe: GEMM2 no longer reads xcat)

    prep_kernel<<<dim3(3584), 256, 0, stream>>>(x, qmask, dia_len,
                                                W_self, W_msg, W_out,
                                                xcat, wt_cat, wt_out);
    gemm_bt<2048, 1><<<dim3(512), 512, 0, stream>>>(xcat, wt_cat, b_self, b_msg,
                                                    x, dia_len, rbuf, nullptr);
    gemm_bt<1024, 2><<<dim3(512), 512, 0, stream>>>(rbuf, wt_out, b_out, nullptr,
                                                    x, nullptr, nullptr, zbuf);
    ln_kernel<<<dim3(8192), 256, 0, stream>>>(zbuf, gamma, beta, out);
}